// Round 20
// baseline (290.741 us; speedup 1.0000x reference)
//
#include <hip/hip_runtime.h>
#include <math.h>

constexpr int L = 8192;
constexpr int B = 4;
constexpr int D = 512;
constexpr int NDIM = 16;
constexpr int Z = 128;
constexpr float NEGF = -50000.0f;
constexpr int CCL = 32;      // conv chunk length (2048 blocks -> 8 waves/SIMD)
constexpr int NCH = L / CCL; // 256 chunks
constexpr int FMAX = 64;     // max fixup rows

typedef short s16x8 __attribute__((ext_vector_type(8)));
typedef float f32x4 __attribute__((ext_vector_type(4)));

typedef __attribute__((address_space(1))) const void* as1cv;
typedef __attribute__((address_space(3))) void* as3v;

__device__ __forceinline__ void gld16(const void* g, void* l) {
  __builtin_amdgcn_global_load_lds((as1cv)g, (as3v)l, 16, 0, 0);
}

__device__ __forceinline__ unsigned short f2bf(float f) {
  unsigned u = __builtin_bit_cast(unsigned, f);
  u += 0x7fffu + ((u >> 16) & 1u);
  return (unsigned short)(u >> 16);
}
__device__ __forceinline__ float bf2f(unsigned short h) {
  return __builtin_bit_cast(float, (unsigned)h << 16);
}

// VALU-only cross-lane add: acc += dpp_move(acc, ctrl) (old=0 for masked lanes)
#define DPPADD(acc, ctrl, rmask)                                                   \
  {                                                                                \
    int _mv = __builtin_amdgcn_update_dpp(0, __builtin_bit_cast(int, acc),         \
                                          ctrl, rmask, 0xf, false);                \
    acc += __builtin_bit_cast(float, _mv);                                         \
  }

// ---------------- 1. per-(d,n) decay q, coeff c, chunk decay powers ----------------
__global__ __launch_bounds__(256) void k_prep(const float* __restrict__ delta,
                                              const float* __restrict__ alpha,
                                              const float* __restrict__ beta,
                                              const float* __restrict__ gamma,
                                              double* __restrict__ qdn,
                                              double* __restrict__ cdn,
                                              double* __restrict__ rp1,
                                              double* __restrict__ rp2,
                                              float* __restrict__ qf,
                                              float* __restrict__ cf,
                                              float* __restrict__ r1f,
                                              float* __restrict__ r2f,
                                              float* __restrict__ r3f,
                                              int* __restrict__ fcnt) {
  int i = blockIdx.x * 256 + threadIdx.x;
  if (i == 0) *fcnt = 0;
  if (i >= D * NDIM) return;
  double p = 1.0 / (1.0 + exp(-(double)delta[i]));
  double a = 1.0 / (1.0 + exp(-(double)alpha[i]));
  double q = 1.0 - p * a;
  double c = p * (double)beta[i] * (double)gamma[i] * 0.25;  // scale = 1/sqrt(NDIM)
  qdn[i] = q; cdn[i] = c;
  double q2 = q * q, q4 = q2 * q2, q8 = q4 * q4;
  double q16 = q8 * q8, q32 = q16 * q16, q64 = q32 * q32;
  rp1[i] = q64;
  rp2[i] = q64 * q64;
  qf[i] = (float)q; cf[i] = (float)c;
  r1f[i] = (float)q32;
  r2f[i] = (float)q64;
  r3f[i] = (float)(q64 * q32);
}

// ---------------- 1b. rotary cos/sin table (f32 trig) ----------------
__global__ __launch_bounds__(256) void k_tab(float2* __restrict__ tab) {
  int tid = blockIdx.x * 256 + threadIdx.x;   // j*64 + i
  int i = tid & 63, j = tid >> 6;
  float freq = __expf(((float)(-2 * i) / 128.0f) * 9.210340371976184f);  // ln(10000)
  float angf = (float)j * freq;
  float sa, ca;
  __sincosf(angf, &sa, &ca);
  float2 r; r.x = ca; r.y = sa;
  tab[tid] = r;
}

// ---------------- 2a. conv phase A (fp32): per-chunk zero-init scan -> E ----------------
__global__ __launch_bounds__(256, 4) void k_convA(const float* __restrict__ x,
                                                  const float* __restrict__ qf,
                                                  float* __restrict__ E) {
  int bx = blockIdx.x;
  int tile = bx & 63, dg = (bx >> 6) & 7, b = bx >> 9;
  int dl = threadIdx.x & 63, cl = threadIdx.x >> 6;
  int dgl = dg * 64 + dl;
  int t = tile * 4 + cl;
  float q[NDIM], s[NDIM];
#pragma unroll
  for (int n = 0; n < NDIM; ++n) { q[n] = qf[dgl * NDIM + n]; s[n] = 0.f; }
  const float* xp = x + ((size_t)(t * CCL) * B + b) * D + dgl;
  float xv[CCL];
#pragma unroll
  for (int u = 0; u < CCL; ++u) xv[u] = xp[u * (B * D)];
#pragma unroll
  for (int u = 0; u < CCL; ++u) {
#pragma unroll
    for (int n = 0; n < NDIM; ++n) s[n] = fmaf(q[n], s[n], xv[u]);
  }
  float* eb = E + ((size_t)(b * NCH + t) * NDIM) * 512 + dgl;
#pragma unroll
  for (int n = 0; n < NDIM; ++n) eb[(size_t)n * 512] = s[n];
}

// ---------------- 2b. conv phase C (fp32): 4-term carry, mx bf16 + DPP Wp dot ----------------
__global__ __launch_bounds__(256, 4) void k_convC(const float* __restrict__ x,
                                                  const float* __restrict__ omega,
                                                  const float* __restrict__ qf,
                                                  const float* __restrict__ cf,
                                                  const float* __restrict__ r1f,
                                                  const float* __restrict__ r2f,
                                                  const float* __restrict__ r3f,
                                                  const float* __restrict__ E,
                                                  const float* __restrict__ Wp,
                                                  unsigned short* __restrict__ mxb,
                                                  float* __restrict__ pdot) {
  int bx = blockIdx.x;
  int tile = bx & 63, dg = (bx >> 6) & 7, b = bx >> 9;
  int dl = threadIdx.x & 63, cl = threadIdx.x >> 6;
  int dgl = dg * 64 + dl;
  int t = tile * 4 + cl;
  float q[NDIM], c[NDIM], s[NDIM];
#pragma unroll
  for (int n = 0; n < NDIM; ++n) {
    q[n] = qf[dgl * NDIM + n];
    c[n] = cf[dgl * NDIM + n];
    s[n] = 0.f;
  }
  if (t >= 1) {
    const float* e1 = E + ((size_t)(b * NCH + t - 1) * NDIM) * 512 + dgl;
#pragma unroll
    for (int n = 0; n < NDIM; ++n) s[n] = e1[(size_t)n * 512];
  }
  if (t >= 2) {
    const float* e2 = E + ((size_t)(b * NCH + t - 2) * NDIM) * 512 + dgl;
#pragma unroll
    for (int n = 0; n < NDIM; ++n) s[n] = fmaf(r1f[dgl * NDIM + n], e2[(size_t)n * 512], s[n]);
  }
  if (t >= 3) {
    const float* e3 = E + ((size_t)(b * NCH + t - 3) * NDIM) * 512 + dgl;
#pragma unroll
    for (int n = 0; n < NDIM; ++n) s[n] = fmaf(r2f[dgl * NDIM + n], e3[(size_t)n * 512], s[n]);
  }
  if (t >= 4) {
    const float* e4 = E + ((size_t)(b * NCH + t - 4) * NDIM) * 512 + dgl;
#pragma unroll
    for (int n = 0; n < NDIM; ++n) s[n] = fmaf(r3f[dgl * NDIM + n], e4[(size_t)n * 512], s[n]);
  }
  float om = omega[dgl];
  float wp = Wp[dgl];
  const float* xp = x + ((size_t)(t * CCL) * B + b) * D + dgl;
  unsigned short* mp = mxb + ((size_t)b * L + t * CCL) * 512 + dgl;
  float* pp = pdot + ((size_t)(b * L + t * CCL)) * 8 + dg;
  float xv[CCL];
#pragma unroll
  for (int u = 0; u < CCL; ++u) xv[u] = xp[u * (B * D)];
#pragma unroll
  for (int u = 0; u < CCL; ++u) {
#pragma unroll
    for (int n = 0; n < NDIM; ++n) s[n] = fmaf(q[n], s[n], xv[u]);
    float p0 = c[0] * s[0], p1 = c[1] * s[1], p2 = c[2] * s[2], p3 = c[3] * s[3];
    p0 = fmaf(c[4], s[4], p0);  p1 = fmaf(c[5], s[5], p1);
    p2 = fmaf(c[6], s[6], p2);  p3 = fmaf(c[7], s[7], p3);
    p0 = fmaf(c[8], s[8], p0);  p1 = fmaf(c[9], s[9], p1);
    p2 = fmaf(c[10], s[10], p2); p3 = fmaf(c[11], s[11], p3);
    p0 = fmaf(c[12], s[12], p0); p1 = fmaf(c[13], s[13], p1);
    p2 = fmaf(c[14], s[14], p2); p3 = fmaf(c[15], s[15], p3);
    float conv = (p0 + p1) + (p2 + p3);
    float m = fmaf(xv[u], om, conv);
    float v = m / (1.0f + __expf(-m));     // silu
    mp[(size_t)u * 512] = f2bf(v);
    float pd = v * wp;
    DPPADD(pd, 0x111, 0xf);   // row_shr:1
    DPPADD(pd, 0x112, 0xf);   // row_shr:2
    DPPADD(pd, 0x114, 0xf);   // row_shr:4
    DPPADD(pd, 0x118, 0xf);   // row_shr:8
    DPPADD(pd, 0x142, 0xa);   // row_bcast15
    DPPADD(pd, 0x143, 0x8);   // row_bcast31
    if (dl == 63) pp[(size_t)u * 8] = pd;
  }
}

// ---------------- 3. logit combine, pi, sel, flag boundary rows ----------------
__global__ __launch_bounds__(256) void k_logitc(const float* __restrict__ pdot,
                                                const float* __restrict__ bp,
                                                const float* __restrict__ temp,
                                                float* __restrict__ pi,
                                                int* __restrict__ selb,
                                                int* __restrict__ fcnt,
                                                int* __restrict__ flags) {
  int rid = blockIdx.x * 256 + threadIdx.x;
  const float* pr = pdot + (size_t)rid * 8;
  double acc = 0.0;
#pragma unroll
  for (int j = 0; j < 8; ++j) acc += (double)pr[j];
  double logit = acc + (double)bp[0];
  pi[rid] = (float)(1.0 / (1.0 + exp(-logit / exp((double)temp[0]))));
  selb[rid] = (logit > 0.0) ? 1 : 0;
  if (fabs(logit) < 1e-4) {            // fp32-ambiguous boundary -> fp64 fixup
    int slot = atomicAdd(fcnt, 1);
    if (slot < FMAX) flags[slot] = rid;
  }
}

// ---------------- 3b. fp64 fixup ----------------
__global__ __launch_bounds__(256) void k_fix(const int* __restrict__ fcnt,
                                             const int* __restrict__ flags,
                                             const float* __restrict__ x,
                                             const double* __restrict__ qdn,
                                             const double* __restrict__ cdn,
                                             const double* __restrict__ rp1,
                                             const double* __restrict__ rp2,
                                             const float* __restrict__ omega,
                                             const float* __restrict__ Wp,
                                             double* __restrict__ pfix) {
  int nb = blockIdx.x;
  int fi = nb >> 3, dblk = nb & 7;
  int count = *fcnt; if (count > FMAX) count = FMAX;
  if (fi >= count) return;
  int rid = flags[fi];
  int b = rid >> 13, l = rid & (L - 1);
  int t = l >> 6, io = l & 63;
  int sub = threadIdx.x >> 6, dl = threadIdx.x & 63;
  int d = dblk * 64 + dl;
  double q[NDIM], s[NDIM];
#pragma unroll
  for (int n = 0; n < NDIM; ++n) { q[n] = qdn[d * NDIM + n]; s[n] = 0.0; }
  int c0 = (sub < 3) ? (t - 3 + sub) : t;
  int steps = (sub < 3) ? 64 : (io + 1);
  if (c0 >= 0) {
    const float* xp = x + ((size_t)(c0 * 64) * B + b) * D + d;
    for (int i = 0; i < steps; ++i) {
      double xv = (double)xp[(size_t)i * (B * D)];
#pragma unroll
      for (int n = 0; n < NDIM; ++n) s[n] = fma(q[n], s[n], xv);
    }
  }
  __shared__ double Esm[4][64][NDIM];   // 32 KB
#pragma unroll
  for (int n = 0; n < NDIM; ++n) Esm[sub][dl][n] = s[n];
  __syncthreads();
  if (sub == 3) {
    double sfin[NDIM];
#pragma unroll
    for (int n = 0; n < NDIM; ++n) {
      double base = q[n], r = 1.0;
      int e = io + 1;
      while (e) { if (e & 1) r *= base; base *= base; e >>= 1; }
      double S = Esm[2][dl][n] + rp1[d * NDIM + n] * Esm[1][dl][n] + rp2[d * NDIM + n] * Esm[0][dl][n];
      sfin[n] = Esm[3][dl][n] + r * S;
    }
    double conv = 0.0;
#pragma unroll
    for (int n = 0; n < NDIM; ++n) conv = fma(cdn[d * NDIM + n], sfin[n], conv);
    double xv = (double)x[((size_t)l * B + b) * D + d];
    double m = conv + xv * (double)omega[d];
    double mxd = m / (1.0 + exp(-m));
    double v = mxd * (double)Wp[d];
#pragma unroll
    for (int off = 32; off; off >>= 1) v += __shfl_down(v, off, 64);
    if (dl == 0) pfix[fi * 8 + dblk] = v;
  }
}

__global__ __launch_bounds__(64) void k_fix2(const int* __restrict__ fcnt,
                                             const int* __restrict__ flags,
                                             const double* __restrict__ pfix,
                                             const float* __restrict__ bp,
                                             const float* __restrict__ temp,
                                             float* __restrict__ pi,
                                             int* __restrict__ selb) {
  int fi = threadIdx.x;
  int count = *fcnt; if (count > FMAX) count = FMAX;
  if (fi >= count) return;
  double s = 0.0;
#pragma unroll
  for (int j = 0; j < 8; ++j) s += pfix[fi * 8 + j];
  double logit = s + (double)bp[0];
  int rid = flags[fi];
  selb[rid] = (logit > 0.0) ? 1 : 0;
  pi[rid] = (float)(1.0 / (1.0 + exp(-logit / exp((double)temp[0]))));
}

// ---------------- 4. per-batch scan (+ src tail fill) ----------------
__global__ __launch_bounds__(256) void k_scan(const int* __restrict__ selb,
                                              int* __restrict__ idx,
                                              int* __restrict__ src,
                                              int* __restrict__ counts) {
  int b = blockIdx.x;
  int t = threadIdx.x;
  __shared__ int part[256];
  const int PER = L / 256;
  int base = b * L + t * PER;
  int loc[PER];
  int cnt = 0;
#pragma unroll
  for (int i = 0; i < PER; ++i) { loc[i] = selb[base + i]; cnt += loc[i]; }
  part[t] = cnt;
  __syncthreads();
  for (int off = 1; off < 256; off <<= 1) {
    int v = (t >= off) ? part[t - off] : 0;
    __syncthreads();
    part[t] += v;
    __syncthreads();
  }
  int run = (t == 0) ? 0 : part[t - 1];
#pragma unroll
  for (int i = 0; i < PER; ++i) {
    int sflag = loc[i];
    run += sflag;
    idx[base + i] = sflag ? run : 0;
    if (sflag) src[b * L + run - 1] = t * PER + i;
  }
  if (t == 255) counts[b] = part[255];
  __syncthreads();
  int total = part[255];
  for (int i2 = total + t; i2 < L; i2 += 256) src[b * L + i2] = 0;  // finite gather for rows >= count
}

// ---------------- 5b. weight transpose+convert ----------------
__global__ __launch_bounds__(256) void k_wt(const float* __restrict__ Wm,
                                            unsigned short* __restrict__ Wt, int N) {
  int idx = blockIdx.x * 256 + threadIdx.x;   // n*512 + k
  int n = idx >> 9, kk = idx & 511;
  Wt[idx] = f2bf(Wm[(size_t)kk * N + n]);
}

// ---------------- 6. bf16 MFMA GEMM + silu, gathered A rows, early-exit past cnt ----------------
__global__ __launch_bounds__(256) void k_gemm_mfma(const unsigned short* __restrict__ mxb,
                                                   const int* __restrict__ src,
                                                   const int* __restrict__ counts,
                                                   const unsigned short* __restrict__ Bt,
                                                   float* __restrict__ outF,
                                                   unsigned short* __restrict__ outT,
                                                   int N, int mode) {
  __shared__ char smem[32768];
  char* As = smem;
  char* Bs = smem + 16384;
  int tid = threadIdx.x;
  int w = tid >> 6, l = tid & 63;
  int mtile, ntile;
  if (mode == 1) {
    int lin = blockIdx.y * 256 + blockIdx.x;
    int xcd = lin & 7, loc = lin >> 3;
    mtile = xcd * 32 + (loc >> 2);
    ntile = loc & 3;
  } else {
    mtile = blockIdx.x; ntile = blockIdx.y;
  }
  int m0 = mtile * 128, n0 = ntile * 128;
  int gb = m0 >> 13, j0 = m0 & 8191;
  if (j0 >= counts[gb]) return;   // rows beyond count never consumed
  int wr = w >> 1, wc = w & 1;
  const unsigned short* arow[4];
  const unsigned short* brow[4];
#pragma unroll
  for (int ld = 0; ld < 4; ++ld) {
    int li = w * 4 + ld;
    int row = li * 8 + (l >> 3);
    int col = ((l & 7) ^ (row & 7)) << 3;
    int srow = src[gb * 8192 + j0 + row];
    arow[ld] = mxb + ((size_t)gb * 8192 + srow) * 512 + col;
    brow[ld] = Bt + (size_t)(n0 + row) * 512 + col;
  }
  f32x4 acc[4][4];
  f32x4 zz = {0.f, 0.f, 0.f, 0.f};
#pragma unroll
  for (int mi = 0; mi < 4; ++mi)
#pragma unroll
    for (int ni = 0; ni < 4; ++ni) acc[mi][ni] = zz;

  for (int k0 = 0; k0 < 512; k0 += 64) {
#pragma unroll
    for (int ld = 0; ld < 4; ++ld) {
      int li = w * 4 + ld;
      gld16(arow[ld] + k0, As + li * 1024);
      gld16(brow[ld] + k0, Bs + li * 1024);
    }
    __syncthreads();
    s16x8 af[4][2], bfr[4][2];
#pragma unroll
    for (int kh = 0; kh < 2; ++kh) {
#pragma unroll
      for (int mi = 0; mi < 4; ++mi) {
        int row = wr * 64 + mi * 16 + (l & 15);
        int byte = row * 128 + ((kh * 64 + ((l >> 4) * 16)) ^ ((row & 7) << 4));
        af[mi][kh] = *(const s16x8*)(As + byte);
      }
#pragma unroll
      for (int ni = 0; ni < 4; ++ni) {
        int row = wc * 64 + ni * 16 + (l & 15);
        int byte = row * 128 + ((kh * 64 + ((l >> 4) * 16)) ^ ((row & 7) << 4));
        bfr[ni][kh] = *(const s16x8*)(Bs + byte);
      }
    }
#pragma unroll
    for (int kh = 0; kh < 2; ++kh)
#pragma unroll
      for (int mi = 0; mi < 4; ++mi)
#pragma unroll
        for (int ni = 0; ni < 4; ++ni)
          acc[mi][ni] = __builtin_amdgcn_mfma_f32_16x16x32_bf16(af[mi][kh], bfr[ni][kh], acc[mi][ni], 0, 0, 0);
    __syncthreads();
  }
  if (mode == 0) {
#pragma unroll
    for (int mi = 0; mi < 4; ++mi)
#pragma unroll
      for (int ni = 0; ni < 4; ++ni)
#pragma unroll
        for (int r = 0; r < 4; ++r) {
          float vv = acc[mi][ni][r];
          vv = vv / (1.0f + __expf(-vv));
          int mrow = m0 + wr * 64 + mi * 16 + (l >> 4) * 4 + r;
          int ncol = n0 + wc * 64 + ni * 16 + (l & 15);
          outF[(size_t)mrow * N + ncol] = vv;
        }
  } else {
    // transpose through LDS (XOR-swizzled) for coalesced bf16 stores along L
#pragma unroll
    for (int mi = 0; mi < 4; ++mi)
#pragma unroll
      for (int ni = 0; ni < 4; ++ni)
#pragma unroll
        for (int r = 0; r < 4; ++r) {
          float vv = acc[mi][ni][r];
          vv = vv / (1.0f + __expf(-vv));
          int mrow = wr * 64 + mi * 16 + (l >> 4) * 4 + r;
          int ncol = wc * 64 + ni * 16 + (l & 15);
          int byteoff = ncol * 256 + ((mrow * 2) ^ ((ncol & 7) << 4));
          *(unsigned short*)(smem + byteoff) = f2bf(vv);
        }
    __syncthreads();
#pragma unroll
    for (int it = 0; it < 8; ++it) {
      int ncol = w * 32 + it * 4 + (l >> 4);
      int ch = l & 15;
      int byteoff = ncol * 256 + ((ch * 16) ^ ((ncol & 7) << 4));
      s16x8 vch = *(const s16x8*)(smem + byteoff);
      *(s16x8*)(outT + ((size_t)(gb * 512 + n0 + ncol)) * 8192 + j0 + ch * 8) = vch;
    }
  }
}

// ---------------- 7. rotary -> bf16 q/k (table-based, early-exit past cnt) ----------------
__global__ __launch_bounds__(256) void k_rot(const float* __restrict__ z,
                                             const float2* __restrict__ tab,
                                             const int* __restrict__ counts,
                                             const float* __restrict__ qg,
                                             const float* __restrict__ qb,
                                             const float* __restrict__ kg,
                                             const float* __restrict__ kb,
                                             unsigned short* __restrict__ qo,
                                             unsigned short* __restrict__ ko) {
  int tid = blockIdx.x * 256 + threadIdx.x;
  int i = tid & 63;
  int row = tid >> 6;
  int j = row & (L - 1);
  int b = row >> 13;
  if (j >= counts[b]) return;    // rows beyond count never consumed
  float2 cs = tab[j * 64 + i];
  float cc = cs.x, ss = cs.y;
  size_t base = (size_t)row * Z + 2 * i;
  float z1 = z[base], z2 = z[base + 1];
  float q1 = z1 * qg[2 * i] + qb[2 * i], q2 = z2 * qg[2 * i + 1] + qb[2 * i + 1];
  float k1 = z1 * kg[2 * i] + kb[2 * i], k2 = z2 * kg[2 * i + 1] + kb[2 * i + 1];
  qo[base]     = f2bf(q1 * cc - q2 * ss);
  qo[base + 1] = f2bf(q1 * ss + q2 * cc);
  ko[base]     = f2bf(k1 * cc - k2 * ss);
  ko[base + 1] = f2bf(k1 * ss + k2 * cc);
}

// ---------------- 8. MFMA windowed attention: even-bid interleave -> 1 active block per CU ----------------
// Depth-first packing gives CU_i resident blocks {2i, 2i+1}. Actives live at EVEN bids
// (work item w -> bid 2w), odd bids exit instantly -> every CU gets exactly one active
// block in the initial wavefront (vs 2-actives-on-half-the-CUs in all prior layouts).
__global__ __launch_bounds__(256) void k_attn_mfma(const unsigned short* __restrict__ q,
                                                   const unsigned short* __restrict__ k,
                                                   const unsigned short* __restrict__ vT,
                                                   const float* __restrict__ relb,
                                                   const int* __restrict__ counts,
                                                   const int* __restrict__ src,
                                                   const float* __restrict__ pi,
                                                   const float* __restrict__ x,
                                                   float* __restrict__ out) {
  __shared__ char smem[65536];
  char* A  = smem;             // 32KB: K quarters (2x16KB) -> later Ps
  char* Bv = smem + 32768;     // 32KB: V chunks (2x16KB)
  int tid = threadIdx.x, w = tid >> 6, l = tid & 63;
  int bid = blockIdx.x;
  if (bid & 1) return;                    // odd bids: interleave fillers
  int wk = bid >> 1;                      // work item 0..511
  int n = wk >> 3, b = (wk >> 1) & 3, half = wk & 1;   // n-major decode
  int cnt = counts[b];
  int q0 = n * 128 + half * 64;
  if (q0 >= cnt) return;
  int kbase = n * 128 - 128;
  const size_t rowb = (size_t)b * L;
  int m0 = w * 16;
  int lg = l >> 4;

  auto stageK = [&](int qi, char* buf) {   // K quarter: 64 rows x 128 z
#pragma unroll
    for (int ld = 0; ld < 4; ++ld) {
      int li = w * 4 + ld;                 // 0..15 KB-blocks
      int rowl = li * 4 + (l >> 4);        // 0..63
      int jk = kbase + qi * 64 + rowl;
      if (jk < 0) jk = 0;
      int colb = ((l & 15) * 16) ^ ((rowl & 7) << 4);
      gld16((const char*)(k + (rowb + jk) * Z) + colb, buf + li * 1024);
    }
  };
  auto stageV = [&](int nc, char* buf) {   // V chunk: 32 d-rows x 256 keys
#pragma unroll
    for (int ld = 0; ld < 4; ++ld) {
      int li = w * 4 + ld;
      int row = li * 2 + (l >> 5);         // 0..31
      int colb = ((l & 31) * 16) ^ ((row & 7) << 4);
      int j = kbase + (colb >> 1);
      if (j < 0) j = 0;
      gld16((const char*)(vT + ((size_t)(b * 512 + nc * 32 + row)) * L + j), buf + li * 1024);
    }
  };

  // ---- issue first K quarter + first V chunk immediately ----
  stageK(0, A);
  stageV(0, Bv);

  // ---- Q A-frags direct from global ----
  s16x8 aq[4];
  {
    const unsigned short* qrow = q + (rowb + q0 + m0 + (l & 15)) * Z + lg * 8;
#pragma unroll
    for (int ks = 0; ks < 4; ++ks) aq[ks] = *(const s16x8*)(qrow + ks * 32);
  }

  // ---- QK^T over 4 K quarters, double-buffered ----
  f32x4 s[16];
  f32x4 zz = {0.f, 0.f, 0.f, 0.f};
#pragma unroll
  for (int ni = 0; ni < 16; ++ni) s[ni] = zz;
#pragma unroll
  for (int qi = 0; qi < 4; ++qi) {
    char* cur = A + (qi & 1) * 16384;
    __syncthreads();
    if (qi < 3) stageK(qi + 1, A + ((qi + 1) & 1) * 16384);
#pragma unroll
    for (int ni4 = 0; ni4 < 4; ++ni4) {
      int ni = qi * 4 + ni4;
      int rowl = ni4 * 16 + (l & 15);
      int rb = rowl * 256, sw = (rowl & 7) << 4;
#pragma unroll
      for (int ks = 0; ks < 4; ++ks) {
        s16x8 bk = *(const s16x8*)(cur + rb + ((ks * 64 + lg * 16) ^ sw));
        s[ni] = __builtin_amdgcn_mfma_f32_16x16x32_bf16(aq[ks], bk, s[ni], 0, 0, 0);
      }
    }
  }
  __syncthreads();   // all waves done reading K buffers -> region A writable as Ps

  // ---- softmax (in-register) ----
  int rgrp = lg * 4;
  float mxr[4] = {-3e38f, -3e38f, -3e38f, -3e38f};
#pragma unroll
  for (int ni = 0; ni < 16; ++ni) {
    int col = ni * 16 + (l & 15);
    int kabs = kbase + col;
#pragma unroll
    for (int r = 0; r < 4; ++r) {
      int ww = half * 64 + m0 + rgrp + r;     // query index within window
      bool valid = (kabs >= 0) && (kabs <= n * 128 + ww) && (kabs < cnt);
      float vv = valid ? (s[ni][r] * 0.08838834764831845f + relb[col + 127 - ww]) : NEGF;
      s[ni][r] = vv;
      mxr[r] = fmaxf(mxr[r], vv);
    }
  }
#pragma unroll
  for (int r = 0; r < 4; ++r)
    for (int off = 1; off < 16; off <<= 1)
      mxr[r] = fmaxf(mxr[r], __shfl_xor(mxr[r], off, 64));
  float smr[4] = {0.f, 0.f, 0.f, 0.f};
#pragma unroll
  for (int ni = 0; ni < 16; ++ni)
#pragma unroll
    for (int r = 0; r < 4; ++r) {
      float p = __expf(s[ni][r] - mxr[r]);
      s[ni][r] = p;
      smr[r] += p;
    }
#pragma unroll
  for (int r = 0; r < 4; ++r) {
    for (int off = 1; off < 16; off <<= 1) smr[r] += __shfl_xor(smr[r], off, 64);
    smr[r] = 1.0f / smr[r];
  }
  // write P (bf16, swizzled) into A
#pragma unroll
  for (int ni = 0; ni < 16; ++ni) {
    int colb2 = (ni * 16 + (l & 15)) * 2;
#pragma unroll
    for (int r = 0; r < 4; ++r) {
      int row = m0 + rgrp + r;
      *(unsigned short*)(A + row * 512 + (colb2 ^ ((row & 7) << 4))) = f2bf(s[ni][r] * smr[r]);
    }
  }
  __syncthreads();   // Ps visible; V chunk 0 drained

  // ---- hoist this wave's 8 P A-frags ----
  s16x8 pa[8];
  {
    int prow = m0 + (l & 15);
    int psw = (prow & 7) << 4;
#pragma unroll
    for (int kt = 0; kt < 8; ++kt)
      pa[kt] = *(const s16x8*)(A + prow * 512 + ((kt * 64 + lg * 16) ^ psw));
  }

  // ---- PV over 16 chunks of 32 d, double-buffered, stores deferred ----
  unsigned hpk[16][4];   // per chunk: 8 outputs packed as bf16 pairs
#pragma unroll
  for (int nc = 0; nc < 16; ++nc) {
    char* cur = Bv + (nc & 1) * 16384;
    if (nc) __syncthreads();               // drains only V loads
    if (nc < 15) stageV(nc + 1, Bv + ((nc + 1) & 1) * 16384);
    f32x4 o[2];
    o[0] = zz; o[1] = zz;
#pragma unroll
    for (int kt = 0; kt < 4; ++kt) {
      s16x8 pa0 = pa[kt * 2];
      s16x8 pa1 = pa[kt * 2 + 1];
#pragma unroll
      for (int ni = 0; ni < 2; ++ni) {
        int vrow = ni * 16 + (l & 15);
        int vsw = (vrow & 7) << 4;
        s16x8 vb0 = *(const s16x8*)(cur + vrow * 512 + ((kt * 128 + lg * 16) ^ vsw));
        s16x8 vb1 = *(const s16x8*)(cur + vrow * 512 + ((kt * 128 + 64 + lg * 16) ^ vsw));
        o[ni] = __builtin_amdgcn_mfma_f32_16x16x32_bf16(pa0, vb0, o[ni], 0, 0, 0);
        o[ni] = __builtin_amdgcn_mfma_f32_16x16x32_bf16(pa1, vb1, o[ni], 0, 0, 0);
      }
    }
#pragma unroll
    for (int ni = 0; ni < 2; ++ni) {
      hpk[nc][ni * 2 + 0] = ((unsigned)f2bf(o[ni][1]) << 16) | f2bf(o[ni][0]);
      hpk[nc][ni * 2 + 1] = ((unsigned)f2bf(o[ni][3]) << 16) | f2bf(o[ni][2]);
    }
  }

  // ---- barrier-free scatter epilogue ----
  int tlr[4]; float pvr[4]; bool vr[4];
#pragma unroll
  for (int r = 0; r < 4; ++r) {
    int jq = q0 + m0 + rgrp + r;
    vr[r] = (jq < cnt);
    int tl = vr[r] ? src[(b << 13) + jq] : 0;
    tlr[r] = tl;
    pvr[r] = pi[(b << 13) + tl];
  }
#pragma unroll
  for (int nc = 0; nc < 16; ++nc)
#pragma unroll
    for (int ni = 0; ni < 2; ++ni)
#pragma unroll
      for (int r = 0; r < 4; ++r)
        if (vr[r]) {
          float hv = bf2f((unsigned short)(hpk[nc][ni * 2 + (r >> 1)] >> ((r & 1) * 16)));
          size_t off = ((size_t)tlr[r] * B + b) * 512 + nc * 32 + ni * 16 + (l & 15);
          out[off] = fmaf(hv, pvr[r], x[off]);
        }
}

// ---------------- 9. fill unselected rows: out = x (gated read) ----------------
__global__ __launch_bounds__(256) void k_fill(const float* __restrict__ x,
                                              const int* __restrict__ idx,
                                              float* __restrict__ out) {
  int e4 = blockIdx.x * 256 + threadIdx.x;     // float4 index
  int rem = e4 >> 7;                            // l*B + b
  int b = rem & 3;
  int l = rem >> 2;
  if (idx[(b << 13) + l] == 0)
    ((float4*)out)[e4] = ((const float4*)x)[e4];
}

extern "C" void kernel_launch(void* const* d_in, const int* in_sizes, int n_in,
                              void* d_out, int out_size, void* d_ws, size_t ws_size,
                              hipStream_t stream) {
  const float* x     = (const float*)d_in[0];
  const float* delta = (const float*)d_in[1];
  const float* alpha = (const float*)d_in[2];
  const float* beta  = (const float*)d_in[3];
  const float* gamma = (const float*)d_in[4];
  const float* omega = (const float*)d_in[5];
  const float* Wp    = (const float*)d_in[6];
  const float* bp    = (const float*)d_in[7];
  const float* temp  = (const float*)d_in[8];
  const float* Wz    = (const float*)d_in[9];
  const float* qg    = (const float*)d_in[10];
  const float* qb    = (const float*)d_in[11];
  const float* kg    = (const float*)d_in[12];
  const float* kb    = (const float*)d_in[13];
  const float* Wv    = (const float*)d_in[14];
  const float* relb  = (const float*)d_in[15];
  (void)in_sizes; (void)n_in; (void)out_size; (void)ws_size;

  char* wsb = (char*)d_ws;
  size_t o = 0;
  auto alloc = [&](size_t bytes) {
    char* p = wsb + o;
    o += (bytes + 255) & ~(size_t)255;
    return p;
  };
  unsigned short* mxb  = (unsigned short*)alloc((size_t)B * L * D * 2);         // bf16 mx, 32MB
  float* Ebuf          = (float*)alloc((size_t)B * NCH * NDIM * 512 * 4);       // 33.6MB
  float* zb            = (float*)alloc((size_t)B * L * Z * 4);
  unsigned short* qb2  = (unsigned short*)alloc((size_t)B * L * Z * 2);
  unsigned short* kb2  = (unsigned short*)alloc((size_t)B * L * Z * 2);
  unsigned short* vTb  = (unsigned short*)alloc((size_t)B * D * L * 2);         // v^T [B][D][L]
  unsigned short* wzt  = (unsigned short*)alloc((size_t)Z * 512 * 2);
  unsigned short* wvt  = (unsigned short*)alloc((size_t)D * 512 * 2);
  float2* tab = (float2*)alloc((size_t)L * 64 * 8);
  float* pdot = (float*)alloc((size_t)B * L * 8 * 4);
  float* pib  = (float*)alloc((size_t)B * L * 4);
  int* selb   = (int*)alloc((size_t)B * L * 4);
  int* idx    = (int*)alloc((size_t)B * L * 4);
  int* src    = (int*)alloc((size_t)B * L * 4);
  int* cnt    = (int*)alloc(256);
  double* qdn = (double*)alloc((size_t)D * NDIM * 8);
  double* cdn = (double*)alloc((size_t)D * NDIM * 8);
  double* rp1 = (double*)alloc((size_t)D * NDIM * 8);
  double* rp2 = (double*)alloc((size_t)D * NDIM * 8);
  float* qf   = (float*)alloc((size_t)D * NDIM * 4);
  float* cf   = (float*)alloc((size_t)D * NDIM * 4);
  float* r1f  = (float*)alloc((size_t)D * NDIM * 4);
  float* r2f  = (float*)alloc((size_t)D * NDIM * 4);
  float* r3f  = (float*)alloc((size_t)D * NDIM * 4);
  int* fcnt   = (int*)alloc(256);
  int* flags  = (int*)alloc(FMAX * 4);
  double* pfix = (double*)alloc((size_t)FMAX * 8 * 8);

  k_prep<<<(D * NDIM + 255) / 256, 256, 0, stream>>>(delta, alpha, beta, gamma,
                                                     qdn, cdn, rp1, rp2, qf, cf, r1f, r2f, r3f, fcnt);
  k_tab<<<L * 64 / 256, 256, 0, stream>>>(tab);
  k_convA<<<B * 8 * 64, 256, 0, stream>>>(x, qf, Ebuf);
  k_convC<<<B * 8 * 64, 256, 0, stream>>>(x, omega, qf, cf, r1f, r2f, r3f, Ebuf, Wp, mxb, pdot);
  k_logitc<<<B * L / 256, 256, 0, stream>>>(pdot, bp, temp, pib, selb, fcnt, flags);
  k_fix<<<FMAX * 8, 256, 0, stream>>>(fcnt, flags, x, qdn, cdn, rp1, rp2, omega, Wp, pfix);
  k_fix2<<<1, 64, 0, stream>>>(fcnt, flags, pfix, bp, temp, pib, selb);
  k_scan<<<B, 256, 0, stream>>>(selb, idx, src, cnt);
  k_wt<<<Z * 512 / 256, 256, 0, stream>>>(Wz, wzt, Z);
  k_wt<<<D * 512 / 256, 256, 0, stream>>>(Wv, wvt, D);
  k_gemm_mfma<<<dim3(256, 1), 256, 0, stream>>>(mxb, src, cnt, wzt, zb, vTb, Z, 0);
  k_gemm_mfma<<<dim3(256, 4), 256, 0, stream>>>(mxb, src, cnt, wvt, zb, vTb, D, 1);
  k_rot<<<B * L * (Z / 2) / 256, 256, 0, stream>>>(zb, tab, cnt, qg, qb, kg, kb, qb2, kb2);
  k_fill<<<(int)((size_t)L * B * D / 4 / 256), 256, 0, stream>>>(x, idx, (float*)d_out);
  k_attn_mfma<<<1024, 256, 0, stream>>>(qb2, kb2, vTb, relb, cnt, src, pib, x, (float*)d_out);
}

// Round 21
// 223.460 us; speedup vs baseline: 1.3011x; 1.3011x over previous
//
#include <hip/hip_runtime.h>
#include <math.h>

constexpr int L = 8192;
constexpr int B = 4;
constexpr int D = 512;
constexpr int NDIM = 16;
constexpr int Z = 128;
constexpr float NEGF = -50000.0f;
constexpr int CCL = 64;      // conv chunk length
constexpr int NCH = L / CCL; // 128 chunks
constexpr int FMAX = 64;     // max fixup rows

typedef short s16x8 __attribute__((ext_vector_type(8)));
typedef float f32x4 __attribute__((ext_vector_type(4)));

typedef __attribute__((address_space(1))) const void* as1cv;
typedef __attribute__((address_space(3))) void* as3v;

__device__ __forceinline__ void gld16(const void* g, void* l) {
  __builtin_amdgcn_global_load_lds((as1cv)g, (as3v)l, 16, 0, 0);
}

__device__ __forceinline__ unsigned short f2bf(float f) {
  unsigned u = __builtin_bit_cast(unsigned, f);
  u += 0x7fffu + ((u >> 16) & 1u);
  return (unsigned short)(u >> 16);
}

// VALU-only cross-lane add: acc += dpp_move(acc, ctrl) (old=0 for masked lanes)
#define DPPADD(acc, ctrl, rmask)                                                   \
  {                                                                                \
    int _mv = __builtin_amdgcn_update_dpp(0, __builtin_bit_cast(int, acc),         \
                                          ctrl, rmask, 0xf, false);                \
    acc += __builtin_bit_cast(float, _mv);                                         \
  }

// ---------------- 1. per-(d,n) decay q, coeff c, chunk decay powers ----------------
__global__ __launch_bounds__(256) void k_prep(const float* __restrict__ delta,
                                              const float* __restrict__ alpha,
                                              const float* __restrict__ beta,
                                              const float* __restrict__ gamma,
                                              double* __restrict__ qdn,
                                              double* __restrict__ cdn,
                                              double* __restrict__ rp1,
                                              double* __restrict__ rp2,
                                              float* __restrict__ qf,
                                              float* __restrict__ cf,
                                              float* __restrict__ r1f,
                                              float* __restrict__ r2f,
                                              int* __restrict__ fcnt) {
  int i = blockIdx.x * 256 + threadIdx.x;
  if (i == 0) *fcnt = 0;
  if (i >= D * NDIM) return;
  double p = 1.0 / (1.0 + exp(-(double)delta[i]));
  double a = 1.0 / (1.0 + exp(-(double)alpha[i]));
  double q = 1.0 - p * a;
  double c = p * (double)beta[i] * (double)gamma[i] * 0.25;  // scale = 1/sqrt(NDIM)
  qdn[i] = q; cdn[i] = c;
  double q2 = q * q, q4 = q2 * q2, q8 = q4 * q4;
  double q16 = q8 * q8, q32 = q16 * q16, q64 = q32 * q32;
  rp1[i] = q64;
  rp2[i] = q64 * q64;
  qf[i] = (float)q; cf[i] = (float)c;
  r1f[i] = (float)q64; r2f[i] = (float)(q64 * q64);
}

// ---------------- 1b. rotary cos/sin table (fp64 trig once) ----------------
__global__ __launch_bounds__(256) void k_tab(float2* __restrict__ tab) {
  int tid = blockIdx.x * 256 + threadIdx.x;   // j*64 + i
  int i = tid & 63, j = tid >> 6;
  double freq = exp(((double)(-2 * i) / 128.0) * log(10000.0));
  float angf = (float)j * (float)freq;        // reference's f32 angle rounding
  double sa, ca;
  sincos((double)angf, &sa, &ca);
  float2 r; r.x = (float)ca; r.y = (float)sa;
  tab[tid] = r;
}

// ---------------- 2a. conv phase A (fp32): per-chunk zero-init scan -> E ----------------
// launch_bounds(256,4): grid is 4 blocks/CU anyway; allow ~128 VGPR so the
// 32-deep x-load batch stays live in registers.
__global__ __launch_bounds__(256, 4) void k_convA(const float* __restrict__ x,
                                                  const float* __restrict__ qf,
                                                  float* __restrict__ E) {
  int bx = blockIdx.x;
  int tile = bx & 31, dg = (bx >> 5) & 7, b = bx >> 8;
  int dl = threadIdx.x & 63, cl = threadIdx.x >> 6;
  int dgl = dg * 64 + dl;
  int t = tile * 4 + cl;
  float q[NDIM], s[NDIM];
#pragma unroll
  for (int n = 0; n < NDIM; ++n) { q[n] = qf[dgl * NDIM + n]; s[n] = 0.f; }
  const float* xp = x + ((size_t)(t * CCL) * B + b) * D + dgl;
#pragma unroll
  for (int ii = 0; ii < CCL; ii += 32) {
    float xv[32];
#pragma unroll
    for (int u = 0; u < 32; ++u) xv[u] = xp[(ii + u) * (B * D)];
#pragma unroll
    for (int u = 0; u < 32; ++u) {
#pragma unroll
      for (int n = 0; n < NDIM; ++n) s[n] = fmaf(q[n], s[n], xv[u]);
    }
  }
  float* eb = E + ((size_t)(b * NCH + t) * NDIM) * 512 + dgl;
#pragma unroll
  for (int n = 0; n < NDIM; ++n) eb[(size_t)n * 512] = s[n];
}

// ---------------- 2b. conv phase C (fp32): carry via 3-term series, mx bf16 + DPP Wp dot ----------------
__global__ __launch_bounds__(256, 4) void k_convC(const float* __restrict__ x,
                                                  const float* __restrict__ omega,
                                                  const float* __restrict__ qf,
                                                  const float* __restrict__ cf,
                                                  const float* __restrict__ r1f,
                                                  const float* __restrict__ r2f,
                                                  const float* __restrict__ E,
                                                  const float* __restrict__ Wp,
                                                  unsigned short* __restrict__ mxb,
                                                  float* __restrict__ pdot) {
  int bx = blockIdx.x;
  int tile = bx & 31, dg = (bx >> 5) & 7, b = bx >> 8;
  int dl = threadIdx.x & 63, cl = threadIdx.x >> 6;
  int dgl = dg * 64 + dl;
  int t = tile * 4 + cl;
  float q[NDIM], c[NDIM], s[NDIM];
#pragma unroll
  for (int n = 0; n < NDIM; ++n) {
    q[n] = qf[dgl * NDIM + n];
    c[n] = cf[dgl * NDIM + n];
    s[n] = 0.f;
  }
  if (t >= 1) {
    const float* e1 = E + ((size_t)(b * NCH + t - 1) * NDIM) * 512 + dgl;
#pragma unroll
    for (int n = 0; n < NDIM; ++n) s[n] = e1[(size_t)n * 512];
  }
  if (t >= 2) {
    const float* e2 = E + ((size_t)(b * NCH + t - 2) * NDIM) * 512 + dgl;
#pragma unroll
    for (int n = 0; n < NDIM; ++n) s[n] = fmaf(r1f[dgl * NDIM + n], e2[(size_t)n * 512], s[n]);
  }
  if (t >= 3) {
    const float* e3 = E + ((size_t)(b * NCH + t - 3) * NDIM) * 512 + dgl;
#pragma unroll
    for (int n = 0; n < NDIM; ++n) s[n] = fmaf(r2f[dgl * NDIM + n], e3[(size_t)n * 512], s[n]);
  }
  float om = omega[dgl];
  float wp = Wp[dgl];
  const float* xp = x + ((size_t)(t * CCL) * B + b) * D + dgl;
  unsigned short* mp = mxb + ((size_t)b * L + t * CCL) * 512 + dgl;
  float* pp = pdot + ((size_t)(b * L + t * CCL)) * 8 + dg;
#pragma unroll
  for (int ii = 0; ii < CCL; ii += 32) {
    float xv[32];
#pragma unroll
    for (int u = 0; u < 32; ++u) xv[u] = xp[(ii + u) * (B * D)];
#pragma unroll
    for (int u = 0; u < 32; ++u) {
      int i = ii + u;
#pragma unroll
      for (int n = 0; n < NDIM; ++n) s[n] = fmaf(q[n], s[n], xv[u]);
      float p0 = c[0] * s[0], p1 = c[1] * s[1], p2 = c[2] * s[2], p3 = c[3] * s[3];
      p0 = fmaf(c[4], s[4], p0);  p1 = fmaf(c[5], s[5], p1);
      p2 = fmaf(c[6], s[6], p2);  p3 = fmaf(c[7], s[7], p3);
      p0 = fmaf(c[8], s[8], p0);  p1 = fmaf(c[9], s[9], p1);
      p2 = fmaf(c[10], s[10], p2); p3 = fmaf(c[11], s[11], p3);
      p0 = fmaf(c[12], s[12], p0); p1 = fmaf(c[13], s[13], p1);
      p2 = fmaf(c[14], s[14], p2); p3 = fmaf(c[15], s[15], p3);
      float conv = (p0 + p1) + (p2 + p3);
      float m = fmaf(xv[u], om, conv);
      float v = m / (1.0f + __expf(-m));     // silu
      mp[(size_t)i * 512] = f2bf(v);
      float pd = v * wp;
      DPPADD(pd, 0x111, 0xf);   // row_shr:1
      DPPADD(pd, 0x112, 0xf);   // row_shr:2
      DPPADD(pd, 0x114, 0xf);   // row_shr:4
      DPPADD(pd, 0x118, 0xf);   // row_shr:8
      DPPADD(pd, 0x142, 0xa);   // row_bcast15
      DPPADD(pd, 0x143, 0x8);   // row_bcast31
      if (dl == 63) pp[(size_t)i * 8] = pd;
    }
  }
}

// ---------------- 3. logit combine, pi, sel, flag boundary rows ----------------
__global__ __launch_bounds__(256) void k_logitc(const float* __restrict__ pdot,
                                                const float* __restrict__ bp,
                                                const float* __restrict__ temp,
                                                float* __restrict__ pi,
                                                int* __restrict__ selb,
                                                int* __restrict__ fcnt,
                                                int* __restrict__ flags) {
  int rid = blockIdx.x * 256 + threadIdx.x;
  const float* pr = pdot + (size_t)rid * 8;
  double acc = 0.0;
#pragma unroll
  for (int j = 0; j < 8; ++j) acc += (double)pr[j];
  double logit = acc + (double)bp[0];
  pi[rid] = (float)(1.0 / (1.0 + exp(-logit / exp((double)temp[0]))));
  selb[rid] = (logit > 0.0) ? 1 : 0;
  if (fabs(logit) < 1e-4) {            // fp32-ambiguous boundary -> fp64 fixup
    int slot = atomicAdd(fcnt, 1);
    if (slot < FMAX) flags[slot] = rid;
  }
}

// ---------------- 3b. fp64 fixup ----------------
__global__ __launch_bounds__(256) void k_fix(const int* __restrict__ fcnt,
                                             const int* __restrict__ flags,
                                             const float* __restrict__ x,
                                             const double* __restrict__ qdn,
                                             const double* __restrict__ cdn,
                                             const double* __restrict__ rp1,
                                             const double* __restrict__ rp2,
                                             const float* __restrict__ omega,
                                             const float* __restrict__ Wp,
                                             double* __restrict__ pfix) {
  int nb = blockIdx.x;
  int fi = nb >> 3, dblk = nb & 7;
  int count = *fcnt; if (count > FMAX) count = FMAX;
  if (fi >= count) return;
  int rid = flags[fi];
  int b = rid >> 13, l = rid & (L - 1);
  int t = l >> 6, io = l & 63;
  int sub = threadIdx.x >> 6, dl = threadIdx.x & 63;
  int d = dblk * 64 + dl;
  double q[NDIM], s[NDIM];
#pragma unroll
  for (int n = 0; n < NDIM; ++n) { q[n] = qdn[d * NDIM + n]; s[n] = 0.0; }
  int c0 = (sub < 3) ? (t - 3 + sub) : t;
  int steps = (sub < 3) ? 64 : (io + 1);
  if (c0 >= 0) {
    const float* xp = x + ((size_t)(c0 * CCL) * B + b) * D + d;
    for (int i = 0; i < steps; ++i) {
      double xv = (double)xp[(size_t)i * (B * D)];
#pragma unroll
      for (int n = 0; n < NDIM; ++n) s[n] = fma(q[n], s[n], xv);
    }
  }
  __shared__ double Esm[4][64][NDIM];   // 32 KB
#pragma unroll
  for (int n = 0; n < NDIM; ++n) Esm[sub][dl][n] = s[n];
  __syncthreads();
  if (sub == 3) {
    double sfin[NDIM];
#pragma unroll
    for (int n = 0; n < NDIM; ++n) {
      double base = q[n], r = 1.0;
      int e = io + 1;
      while (e) { if (e & 1) r *= base; base *= base; e >>= 1; }
      double S = Esm[2][dl][n] + rp1[d * NDIM + n] * Esm[1][dl][n] + rp2[d * NDIM + n] * Esm[0][dl][n];
      sfin[n] = Esm[3][dl][n] + r * S;
    }
    double conv = 0.0;
#pragma unroll
    for (int n = 0; n < NDIM; ++n) conv = fma(cdn[d * NDIM + n], sfin[n], conv);
    double xv = (double)x[((size_t)l * B + b) * D + d];
    double m = conv + xv * (double)omega[d];
    double mxd = m / (1.0 + exp(-m));
    double v = mxd * (double)Wp[d];
#pragma unroll
    for (int off = 32; off; off >>= 1) v += __shfl_down(v, off, 64);
    if (dl == 0) pfix[fi * 8 + dblk] = v;
  }
}

__global__ __launch_bounds__(64) void k_fix2(const int* __restrict__ fcnt,
                                             const int* __restrict__ flags,
                                             const double* __restrict__ pfix,
                                             const float* __restrict__ bp,
                                             const float* __restrict__ temp,
                                             float* __restrict__ pi,
                                             int* __restrict__ selb) {
  int fi = threadIdx.x;
  int count = *fcnt; if (count > FMAX) count = FMAX;
  if (fi >= count) return;
  double s = 0.0;
#pragma unroll
  for (int j = 0; j < 8; ++j) s += pfix[fi * 8 + j];
  double logit = s + (double)bp[0];
  int rid = flags[fi];
  selb[rid] = (logit > 0.0) ? 1 : 0;
  pi[rid] = (float)(1.0 / (1.0 + exp(-logit / exp((double)temp[0]))));
}

// ---------------- 4. per-batch scan (+ src tail fill) ----------------
__global__ __launch_bounds__(256) void k_scan(const int* __restrict__ selb,
                                              int* __restrict__ idx,
                                              int* __restrict__ src,
                                              int* __restrict__ counts) {
  int b = blockIdx.x;
  int t = threadIdx.x;
  __shared__ int part[256];
  const int PER = L / 256;
  int base = b * L + t * PER;
  int loc[PER];
  int cnt = 0;
#pragma unroll
  for (int i = 0; i < PER; ++i) { loc[i] = selb[base + i]; cnt += loc[i]; }
  part[t] = cnt;
  __syncthreads();
  for (int off = 1; off < 256; off <<= 1) {
    int v = (t >= off) ? part[t - off] : 0;
    __syncthreads();
    part[t] += v;
    __syncthreads();
  }
  int run = (t == 0) ? 0 : part[t - 1];
#pragma unroll
  for (int i = 0; i < PER; ++i) {
    int sflag = loc[i];
    run += sflag;
    idx[base + i] = sflag ? run : 0;
    if (sflag) src[b * L + run - 1] = t * PER + i;
  }
  if (t == 255) counts[b] = part[255];
  __syncthreads();
  int total = part[255];
  for (int i2 = total + t; i2 < L; i2 += 256) src[b * L + i2] = 0;  // finite gather for rows >= count
}

// ---------------- 5b. weight transpose+convert ----------------
__global__ __launch_bounds__(256) void k_wt(const float* __restrict__ Wm,
                                            unsigned short* __restrict__ Wt, int N) {
  int idx = blockIdx.x * 256 + threadIdx.x;   // n*512 + k
  int n = idx >> 9, kk = idx & 511;
  Wt[idx] = f2bf(Wm[(size_t)kk * N + n]);
}

// ---------------- 6. bf16 MFMA GEMM + silu, gathered A rows, early-exit past cnt ----------------
__global__ __launch_bounds__(256) void k_gemm_mfma(const unsigned short* __restrict__ mxb,
                                                   const int* __restrict__ src,
                                                   const int* __restrict__ counts,
                                                   const unsigned short* __restrict__ Bt,
                                                   float* __restrict__ outF,
                                                   unsigned short* __restrict__ outT,
                                                   int N, int mode) {
  __shared__ char smem[32768];
  char* As = smem;
  char* Bs = smem + 16384;
  int tid = threadIdx.x;
  int w = tid >> 6, l = tid & 63;
  int mtile, ntile;
  if (mode == 1) {
    int lin = blockIdx.y * 256 + blockIdx.x;
    int xcd = lin & 7, loc = lin >> 3;
    mtile = xcd * 32 + (loc >> 2);
    ntile = loc & 3;
  } else {
    mtile = blockIdx.x; ntile = blockIdx.y;
  }
  int m0 = mtile * 128, n0 = ntile * 128;
  int gb = m0 >> 13, j0 = m0 & 8191;
  if (j0 >= counts[gb]) return;   // rows beyond count never consumed
  int wr = w >> 1, wc = w & 1;
  const unsigned short* arow[4];
  const unsigned short* brow[4];
#pragma unroll
  for (int ld = 0; ld < 4; ++ld) {
    int li = w * 4 + ld;
    int row = li * 8 + (l >> 3);
    int col = ((l & 7) ^ (row & 7)) << 3;
    int srow = src[gb * 8192 + j0 + row];
    arow[ld] = mxb + ((size_t)gb * 8192 + srow) * 512 + col;
    brow[ld] = Bt + (size_t)(n0 + row) * 512 + col;
  }
  f32x4 acc[4][4];
  f32x4 zz = {0.f, 0.f, 0.f, 0.f};
#pragma unroll
  for (int mi = 0; mi < 4; ++mi)
#pragma unroll
    for (int ni = 0; ni < 4; ++ni) acc[mi][ni] = zz;

  for (int k0 = 0; k0 < 512; k0 += 64) {
#pragma unroll
    for (int ld = 0; ld < 4; ++ld) {
      int li = w * 4 + ld;
      gld16(arow[ld] + k0, As + li * 1024);
      gld16(brow[ld] + k0, Bs + li * 1024);
    }
    __syncthreads();
    s16x8 af[4][2], bfr[4][2];
#pragma unroll
    for (int kh = 0; kh < 2; ++kh) {
#pragma unroll
      for (int mi = 0; mi < 4; ++mi) {
        int row = wr * 64 + mi * 16 + (l & 15);
        int byte = row * 128 + ((kh * 64 + ((l >> 4) * 16)) ^ ((row & 7) << 4));
        af[mi][kh] = *(const s16x8*)(As + byte);
      }
#pragma unroll
      for (int ni = 0; ni < 4; ++ni) {
        int row = wc * 64 + ni * 16 + (l & 15);
        int byte = row * 128 + ((kh * 64 + ((l >> 4) * 16)) ^ ((row & 7) << 4));
        bfr[ni][kh] = *(const s16x8*)(Bs + byte);
      }
    }
#pragma unroll
    for (int kh = 0; kh < 2; ++kh)
#pragma unroll
      for (int mi = 0; mi < 4; ++mi)
#pragma unroll
        for (int ni = 0; ni < 4; ++ni)
          acc[mi][ni] = __builtin_amdgcn_mfma_f32_16x16x32_bf16(af[mi][kh], bfr[ni][kh], acc[mi][ni], 0, 0, 0);
    __syncthreads();
  }
  if (mode == 0) {
#pragma unroll
    for (int mi = 0; mi < 4; ++mi)
#pragma unroll
      for (int ni = 0; ni < 4; ++ni)
#pragma unroll
        for (int r = 0; r < 4; ++r) {
          float vv = acc[mi][ni][r];
          vv = vv / (1.0f + __expf(-vv));
          int mrow = m0 + wr * 64 + mi * 16 + (l >> 4) * 4 + r;
          int ncol = n0 + wc * 64 + ni * 16 + (l & 15);
          outF[(size_t)mrow * N + ncol] = vv;
        }
  } else {
    // transpose through LDS (XOR-swizzled) for coalesced bf16 stores along L
#pragma unroll
    for (int mi = 0; mi < 4; ++mi)
#pragma unroll
      for (int ni = 0; ni < 4; ++ni)
#pragma unroll
        for (int r = 0; r < 4; ++r) {
          float vv = acc[mi][ni][r];
          vv = vv / (1.0f + __expf(-vv));
          int mrow = wr * 64 + mi * 16 + (l >> 4) * 4 + r;
          int ncol = wc * 64 + ni * 16 + (l & 15);
          int byteoff = ncol * 256 + ((mrow * 2) ^ ((ncol & 7) << 4));
          *(unsigned short*)(smem + byteoff) = f2bf(vv);
        }
    __syncthreads();
#pragma unroll
    for (int it = 0; it < 8; ++it) {
      int ncol = w * 32 + it * 4 + (l >> 4);
      int ch = l & 15;
      int byteoff = ncol * 256 + ((ch * 16) ^ ((ncol & 7) << 4));
      s16x8 vch = *(const s16x8*)(smem + byteoff);
      *(s16x8*)(outT + ((size_t)(gb * 512 + n0 + ncol)) * 8192 + j0 + ch * 8) = vch;
    }
  }
}

// ---------------- 7. rotary -> bf16 q/k (table-based, early-exit past cnt) ----------------
__global__ __launch_bounds__(256) void k_rot(const float* __restrict__ z,
                                             const float2* __restrict__ tab,
                                             const int* __restrict__ counts,
                                             const float* __restrict__ qg,
                                             const float* __restrict__ qb,
                                             const float* __restrict__ kg,
                                             const float* __restrict__ kb,
                                             unsigned short* __restrict__ qo,
                                             unsigned short* __restrict__ ko) {
  int tid = blockIdx.x * 256 + threadIdx.x;
  int i = tid & 63;
  int row = tid >> 6;
  int j = row & (L - 1);
  int b = row >> 13;
  if (j >= counts[b]) return;    // rows beyond count never consumed
  float2 cs = tab[j * 64 + i];
  float cc = cs.x, ss = cs.y;
  size_t base = (size_t)row * Z + 2 * i;
  float z1 = z[base], z2 = z[base + 1];
  float q1 = z1 * qg[2 * i] + qb[2 * i], q2 = z2 * qg[2 * i + 1] + qb[2 * i + 1];
  float k1 = z1 * kg[2 * i] + kb[2 * i], k2 = z2 * kg[2 * i + 1] + kb[2 * i + 1];
  qo[base]     = f2bf(q1 * cc - q2 * ss);
  qo[base + 1] = f2bf(q1 * ss + q2 * cc);
  ko[base]     = f2bf(k1 * cc - k2 * ss);
  ko[base + 1] = f2bf(k1 * ss + k2 * cc);
}

// ---------------- 8. MFMA windowed attention: half-window (64 q) blocks, 256 thr, 80KB LDS ----------------
// (Measured-best config: 223.7 us total, attn 63.5 us.)
__global__ __launch_bounds__(256) void k_attn_mfma(const unsigned short* __restrict__ q,
                                                   const unsigned short* __restrict__ k,
                                                   const unsigned short* __restrict__ vT,
                                                   const float* __restrict__ relb,
                                                   const int* __restrict__ counts,
                                                   const int* __restrict__ src,
                                                   const float* __restrict__ pi,
                                                   const float* __restrict__ x,
                                                   float* __restrict__ out) {
  __shared__ char smem[81920];
  char* Qs = smem;            // 16KB
  char* Ks = smem + 16384;    // 64KB
  char* Ps = smem;            // 32KB (overlays Qs + Ks[0:16K])
  char* Vs = smem + 32768;    // 32KB (overlays Ks[16K:48K])
  int tid = threadIdx.x, w = tid >> 6, l = tid & 63;
  int bid = blockIdx.x;
  int n = bid & 63, b = (bid >> 6) & 3, half = bid >> 8;
  int cnt = counts[b];
  int q0 = n * 128 + half * 64;          // first query row of this block
  if (q0 >= cnt) return;                 // nothing consumed from this block
  int kbase = n * 128 - 128;
  const size_t rowb = (size_t)b * L;

  // ---- stage Q (64 rows) and K (256 rows) ----
#pragma unroll
  for (int ld = 0; ld < 4; ++ld) {
    int li = w * 4 + ld;
    int row = li * 4 + (l >> 4);
    int colb = ((l & 15) * 16) ^ ((row & 7) << 4);
    gld16((const char*)(q + (rowb + q0 + row) * Z) + colb, Qs + li * 1024);
  }
#pragma unroll
  for (int ld = 0; ld < 16; ++ld) {
    int li = w * 16 + ld;
    int row = li * 4 + (l >> 4);
    int jk = kbase + row; if (jk < 0) jk = 0;
    int colb = ((l & 15) * 16) ^ ((row & 7) << 4);
    gld16((const char*)(k + (rowb + jk) * Z) + colb, Ks + li * 1024);
  }
  __syncthreads();

  // ---- QK^T: wave w owns local q rows [w*16, w*16+16) x 256 keys ----
  int m0 = w * 16;
  f32x4 s[16];
  f32x4 zz = {0.f, 0.f, 0.f, 0.f};
#pragma unroll
  for (int ni = 0; ni < 16; ++ni) s[ni] = zz;
  s16x8 aq[4];
#pragma unroll
  for (int ks = 0; ks < 4; ++ks) {
    int row = m0 + (l & 15);
    int byte = row * 256 + ((ks * 64 + ((l >> 4) * 16)) ^ ((row & 7) << 4));
    aq[ks] = *(const s16x8*)(Qs + byte);
  }
#pragma unroll
  for (int ni = 0; ni < 16; ++ni) {
    int row = ni * 16 + (l & 15);
    int rb = row * 256, sw = (row & 7) << 4;
#pragma unroll
    for (int ks = 0; ks < 4; ++ks) {
      s16x8 bk = *(const s16x8*)(Ks + rb + ((ks * 64 + ((l >> 4) * 16)) ^ sw));
      s[ni] = __builtin_amdgcn_mfma_f32_16x16x32_bf16(aq[ks], bk, s[ni], 0, 0, 0);
    }
  }
  __syncthreads();   // all waves done reading Qs/Ks; Ps/Vs regions now writable

  auto stageV = [&](int nc) {    // V chunk: 64 d-rows x 256 keys
#pragma unroll
    for (int ld = 0; ld < 8; ++ld) {
      int li = w * 8 + ld;
      int row = li * 2 + (l >> 5);
      int colb = ((l & 31) * 16) ^ ((row & 7) << 4);
      int j = kbase + (colb >> 1);
      if (j < 0) j = 0;
      gld16((const char*)(vT + ((size_t)(b * 512 + nc * 64 + row)) * L + j), Vs + li * 1024);
    }
  };
  stageV(0);

  // ---- softmax (in-register) ----
  int rgrp = (l >> 4) * 4;
  float mxr[4] = {-3e38f, -3e38f, -3e38f, -3e38f};
#pragma unroll
  for (int ni = 0; ni < 16; ++ni) {
    int col = ni * 16 + (l & 15);
    int kabs = kbase + col;
#pragma unroll
    for (int r = 0; r < 4; ++r) {
      int ww = half * 64 + m0 + rgrp + r;     // query index within window
      bool valid = (kabs >= 0) && (kabs <= n * 128 + ww) && (kabs < cnt);
      float vv = valid ? (s[ni][r] * 0.08838834764831845f + relb[col + 127 - ww]) : NEGF;
      s[ni][r] = vv;
      mxr[r] = fmaxf(mxr[r], vv);
    }
  }
#pragma unroll
  for (int r = 0; r < 4; ++r)
    for (int off = 1; off < 16; off <<= 1)
      mxr[r] = fmaxf(mxr[r], __shfl_xor(mxr[r], off, 64));
  float smr[4] = {0.f, 0.f, 0.f, 0.f};
#pragma unroll
  for (int ni = 0; ni < 16; ++ni)
#pragma unroll
    for (int r = 0; r < 4; ++r) {
      float p = __expf(s[ni][r] - mxr[r]);
      s[ni][r] = p;
      smr[r] += p;
    }
#pragma unroll
  for (int r = 0; r < 4; ++r) {
    for (int off = 1; off < 16; off <<= 1) smr[r] += __shfl_xor(smr[r], off, 64);
    smr[r] = 1.0f / smr[r];
  }
#pragma unroll
  for (int ni = 0; ni < 16; ++ni) {
    int colb2 = (ni * 16 + (l & 15)) * 2;
#pragma unroll
    for (int r = 0; r < 4; ++r) {
      int row = m0 + rgrp + r;
      *(unsigned short*)(Ps + row * 512 + (colb2 ^ ((row & 7) << 4))) = f2bf(s[ni][r] * smr[r]);
    }
  }
  __syncthreads();   // Ps visible, Vs(0) landed

  // scatter targets for this thread's 4 q-rows
  int tlr[4]; float pvr[4]; bool vr[4];
#pragma unroll
  for (int r = 0; r < 4; ++r) {
    int jq = q0 + m0 + rgrp + r;
    vr[r] = (jq < cnt);
    int tl = vr[r] ? src[(b << 13) + jq] : 0;
    tlr[r] = tl;
    pvr[r] = pi[(b << 13) + tl];
  }

  // ---- PV over 8 chunks of 64 d ----
  for (int nc = 0; nc < 8; ++nc) {
    if (nc) {
      __syncthreads();
      stageV(nc);
      __syncthreads();
    }
    f32x4 o[4];
#pragma unroll
    for (int ni = 0; ni < 4; ++ni) o[ni] = zz;
    int prow = m0 + (l & 15);
    int psw = (prow & 7) << 4;
#pragma unroll
    for (int kt = 0; kt < 4; ++kt) {
      s16x8 pa0 = *(const s16x8*)(Ps + prow * 512 + ((kt * 128 + ((l >> 4) * 16)) ^ psw));
      s16x8 pa1 = *(const s16x8*)(Ps + prow * 512 + ((kt * 128 + 64 + ((l >> 4) * 16)) ^ psw));
#pragma unroll
      for (int ni = 0; ni < 4; ++ni) {
        int vrow = ni * 16 + (l & 15);
        int vsw = (vrow & 7) << 4;
        s16x8 vb0 = *(const s16x8*)(Vs + vrow * 512 + ((kt * 128 + ((l >> 4) * 16)) ^ vsw));
        s16x8 vb1 = *(const s16x8*)(Vs + vrow * 512 + ((kt * 128 + 64 + ((l >> 4) * 16)) ^ vsw));
        o[ni] = __builtin_amdgcn_mfma_f32_16x16x32_bf16(pa0, vb0, o[ni], 0, 0, 0);
        o[ni] = __builtin_amdgcn_mfma_f32_16x16x32_bf16(pa1, vb1, o[ni], 0, 0, 0);
      }
    }
#pragma unroll
    for (int ni = 0; ni < 4; ++ni)
#pragma unroll
      for (int r = 0; r < 4; ++r)
        if (vr[r]) {
          size_t off = ((size_t)tlr[r] * B + b) * 512 + nc * 64 + ni * 16 + (l & 15);
          out[off] = fmaf(o[ni][r], pvr[r], x[off]);
        }
  }
}

// ---------------- 9. fill unselected rows: out = x ----------------
__global__ __launch_bounds__(256) void k_fill(const float* __restrict__ x,
                                              const int* __restrict__ idx,
                                              float* __restrict__ out) {
  int e4 = blockIdx.x * 256 + threadIdx.x;     // float4 index
  int rem = e4 >> 7;                            // l*B + b
  int b = rem & 3;
  int l = rem >> 2;
  if (idx[(b << 13) + l] == 0)
    ((float4*)out)[e4] = ((const float4*)x)[e4];
}

extern "C" void kernel_launch(void* const* d_in, const int* in_sizes, int n_in,
                              void* d_out, int out_size, void* d_ws, size_t ws_size,
                              hipStream_t stream) {
  const float* x     = (const float*)d_in[0];
  const float* delta = (const float*)d_in[1];
  const float* alpha = (const float*)d_in[2];
  const float* beta  = (const float*)d_in[3];
  const float* gamma = (const float*)d_in[4];
  const float* omega = (const float*)d_in[5];
  const float* Wp    = (const float*)d_in[6];
  const float* bp    = (const float*)d_in[7];
  const float* temp  = (const float*)d_in[8];
  const float* Wz    = (const float*)d_in[9];
  const float* qg    = (const float*)d_in[10];
  const float* qb    = (const float*)d_in[11];
  const float* kg    = (const float*)d_in[12];
  const float* kb    = (const float*)d_in[13];
  const float* Wv    = (const float*)d_in[14];
  const float* relb  = (const float*)d_in[15];
  (void)in_sizes; (void)n_in; (void)out_size; (void)ws_size;

  char* wsb = (char*)d_ws;
  size_t o = 0;
  auto alloc = [&](size_t bytes) {
    char* p = wsb + o;
    o += (bytes + 255) & ~(size_t)255;
    return p;
  };
  // [0,32MB) = mxb (bf16 mx); [32MB,48.8MB) = E (dead after convC)
  unsigned short* mxb  = (unsigned short*)alloc((size_t)B * L * D * 4);
  float* Ebuf          = (float*)((char*)mxb + (size_t)B * L * D * 2);
  float* zb            = (float*)alloc((size_t)B * L * Z * 4);
  unsigned short* qb2  = (unsigned short*)alloc((size_t)B * L * Z * 2);
  unsigned short* kb2  = (unsigned short*)alloc((size_t)B * L * Z * 2);
  unsigned short* vTb  = (unsigned short*)alloc((size_t)B * D * L * 2); // v^T [B][D][L]
  unsigned short* wzt  = (unsigned short*)alloc((size_t)Z * 512 * 2);
  unsigned short* wvt  = (unsigned short*)alloc((size_t)D * 512 * 2);
  float2* tab = (float2*)alloc((size_t)L * 64 * 8);
  float* pdot = (float*)alloc((size_t)B * L * 8 * 4);
  float* pib  = (float*)alloc((size_t)B * L * 4);
  int* selb   = (int*)alloc((size_t)B * L * 4);
  int* idx    = (int*)alloc((size_t)B * L * 4);
  int* src    = (int*)alloc((size_t)B * L * 4);
  int* cnt    = (int*)alloc(256);
  double* qdn = (double*)alloc((size_t)D * NDIM * 8);
  double* cdn = (double*)alloc((size_t)D * NDIM * 8);
  double* rp1 = (double*)alloc((size_t)D * NDIM * 8);
  double* rp2 = (double*)alloc((size_t)D * NDIM * 8);
  float* qf   = (float*)alloc((size_t)D * NDIM * 4);
  float* cf   = (float*)alloc((size_t)D * NDIM * 4);
  float* r1f  = (float*)alloc((size_t)D * NDIM * 4);
  float* r2f  = (float*)alloc((size_t)D * NDIM * 4);
  int* fcnt   = (int*)alloc(256);
  int* flags  = (int*)alloc(FMAX * 4);
  double* pfix = (double*)alloc((size_t)FMAX * 8 * 8);

  k_prep<<<(D * NDIM + 255) / 256, 256, 0, stream>>>(delta, alpha, beta, gamma,
                                                     qdn, cdn, rp1, rp2, qf, cf, r1f, r2f, fcnt);
  k_tab<<<L * 64 / 256, 256, 0, stream>>>(tab);
  k_convA<<<B * 8 * 32, 256, 0, stream>>>(x, qf, Ebuf);
  k_convC<<<B * 8 * 32, 256, 0, stream>>>(x, omega, qf, cf, r1f, r2f, Ebuf, Wp, mxb, pdot);
  k_logitc<<<B * L / 256, 256, 0, stream>>>(pdot, bp, temp, pib, selb, fcnt, flags);
  k_fix<<<FMAX * 8, 256, 0, stream>>>(fcnt, flags, x, qdn, cdn, rp1, rp2, omega, Wp, pfix);
  k_fix2<<<1, 64, 0, stream>>>(fcnt, flags, pfix, bp, temp, pib, selb);
  k_scan<<<B, 256, 0, stream>>>(selb, idx, src, cnt);
  k_wt<<<Z * 512 / 256, 256, 0, stream>>>(Wz, wzt, Z);
  k_wt<<<D * 512 / 256, 256, 0, stream>>>(Wv, wvt, D);
  k_gemm_mfma<<<dim3(256, 1), 256, 0, stream>>>(mxb, src, cnt, wzt, zb, vTb, Z, 0);
  k_gemm_mfma<<<dim3(256, 4), 256, 0, stream>>>(mxb, src, cnt, wvt, zb, vTb, D, 1);
  k_rot<<<B * L * (Z / 2) / 256, 256, 0, stream>>>(zb, tab, cnt, qg, qb, kg, kb, qb2, kb2);
  k_fill<<<(int)((size_t)L * B * D / 4 / 256), 256, 0, stream>>>(x, idx, (float*)d_out);
  k_attn_mfma<<<512, 256, 0, stream>>>(qb2, kb2, vTb, relb, cnt, src, pib, x, (float*)d_out);
}